// Round 4
// baseline (322.163 us; speedup 1.0000x reference)
//
#include <hip/hip_runtime.h>

#define LDIM 256
#define NPOS 65536   // 256*256

typedef __attribute__((ext_vector_type(8))) short bf16x8;
typedef __attribute__((ext_vector_type(4))) float f32x4;

static __device__ __forceinline__ unsigned short f2bf(float f) {
  union { float f; unsigned int u; } v; v.f = f;
  unsigned int r = v.u + 0x7fffu + ((v.u >> 16) & 1u);
  return (unsigned short)(r >> 16);
}
static __device__ __forceinline__ float bf2f(unsigned short u) {
  union { unsigned int u; float f; } v; v.u = ((unsigned int)u) << 16;
  return v.f;
}
static __device__ __forceinline__ unsigned int pack2(float a, float b) {
  return (unsigned int)f2bf(a) | ((unsigned int)f2bf(b) << 16);
}
static __device__ __forceinline__ void lgkm_wait() {
  __asm__ volatile("s_waitcnt lgkmcnt(0)" ::: "memory");
}

// ---------------- K0: pack transposed bf16 weights ----------------
// WT[n][k], n in [0,512): Wq^T*(1/sqrt(32)) | Wk^T | Wv^T | Wg^T ; WoT[n][k]=Wo[k][n]
__global__ void k_pack(const float* __restrict__ Wq, const float* __restrict__ Wk,
                       const float* __restrict__ Wv, const float* __restrict__ Wg,
                       const float* __restrict__ Wo,
                       ushort* __restrict__ WT, ushort* __restrict__ WoT) {
  int idx = blockIdx.x * blockDim.x + threadIdx.x;
  if (idx < 512 * 128) {
    int n = idx >> 7, k = idx & 127;
    int nn = n & 127;
    float val;
    if (n < 128)      val = Wq[k * 128 + nn] * 0.17677669529663687f; // fold 1/sqrt(D)
    else if (n < 256) val = Wk[k * 128 + nn];
    else if (n < 384) val = Wv[k * 128 + nn];
    else              val = Wg[k * 128 + nn];
    WT[idx] = f2bf(val);
  } else if (idx < 512 * 128 + 128 * 128) {
    int j = idx - 512 * 128;
    int n = j >> 7, k = j & 127;
    WoT[j] = f2bf(Wo[k * 128 + n]);
  }
}

// ---------------- K1: LayerNorm (streaming) + pairwise bias (transposed bf16) -
// thread = (row = t>>2, quarter q = t&3); biasT[h][k*256+j] for pos=(j,k)
__global__ __launch_bounds__(256) void k_ln(
    const float* __restrict__ in, const float* __restrict__ gamma,
    const float* __restrict__ beta, const float* __restrict__ Wb,
    ushort* __restrict__ x, ushort* __restrict__ biasT) {
  int t = threadIdx.x;
  int row = t >> 2, q = t & 3;
  int pos = blockIdx.x * 64 + row;
  const float* rp = in + (size_t)pos * 128 + q * 32;
  float xv[32];
  float s = 0.f, ss = 0.f;
  #pragma unroll
  for (int o = 0; o < 8; o++) {
    float4 v = ((const float4*)rp)[o];
    xv[o*4+0] = v.x; xv[o*4+1] = v.y; xv[o*4+2] = v.z; xv[o*4+3] = v.w;
    s  += v.x + v.y + v.z + v.w;
    ss += v.x*v.x + v.y*v.y + v.z*v.z + v.w*v.w;
  }
  s  += __shfl_xor(s, 1, 64);  s  += __shfl_xor(s, 2, 64);
  ss += __shfl_xor(ss, 1, 64); ss += __shfl_xor(ss, 2, 64);
  float mu  = s * (1.0f / 128.0f);
  float var = ss * (1.0f / 128.0f) - mu * mu;
  float rs  = rsqrtf(var + 1e-5f);
  float p0 = 0.f, p1 = 0.f, p2 = 0.f, p3 = 0.f;
  const float4* gp  = (const float4*)(gamma + q * 32);
  const float4* bp  = (const float4*)(beta  + q * 32);
  const float4* wbp = (const float4*)(Wb + q * 32 * 4);
  #pragma unroll
  for (int o = 0; o < 8; o++) {
    float4 g4 = gp[o], b4 = bp[o];
    float xn0 = (xv[o*4+0] - mu) * rs * g4.x + b4.x;
    float xn1 = (xv[o*4+1] - mu) * rs * g4.y + b4.y;
    float xn2 = (xv[o*4+2] - mu) * rs * g4.z + b4.z;
    float xn3 = (xv[o*4+3] - mu) * rs * g4.w + b4.w;
    xv[o*4+0] = xn0; xv[o*4+1] = xn1; xv[o*4+2] = xn2; xv[o*4+3] = xn3;
    float4 w0 = wbp[o*4+0], w1 = wbp[o*4+1], w2 = wbp[o*4+2], w3 = wbp[o*4+3];
    p0 += xn0*w0.x + xn1*w1.x + xn2*w2.x + xn3*w3.x;
    p1 += xn0*w0.y + xn1*w1.y + xn2*w2.y + xn3*w3.y;
    p2 += xn0*w0.z + xn1*w1.z + xn2*w2.z + xn3*w3.z;
    p3 += xn0*w0.w + xn1*w1.w + xn2*w2.w + xn3*w3.w;
  }
  p0 += __shfl_xor(p0, 1, 64); p0 += __shfl_xor(p0, 2, 64);
  p1 += __shfl_xor(p1, 1, 64); p1 += __shfl_xor(p1, 2, 64);
  p2 += __shfl_xor(p2, 1, 64); p2 += __shfl_xor(p2, 2, 64);
  p3 += __shfl_xor(p3, 1, 64); p3 += __shfl_xor(p3, 2, 64);
  if (q == 0) {
    int a = pos >> 8, b = pos & 255;           // pos=(j=a, k=b)
    size_t o = (size_t)b * 256 + a;            // biasT[h][k][j]
    biasT[0 * NPOS + o] = f2bf(p0);
    biasT[1 * NPOS + o] = f2bf(p1);
    biasT[2 * NPOS + o] = f2bf(p2);
    biasT[3 * NPOS + o] = f2bf(p3);
  }
  #pragma unroll
  for (int o = 0; o < 4; o++) {
    bf16x8 pk;
    #pragma unroll
    for (int e = 0; e < 8; e++) pk[e] = (short)f2bf(xv[o*8+e]);
    *(bf16x8*)(x + (size_t)pos * 128 + q * 32 + o * 8) = pk;
  }
}

// ---------------- K2: fused QKVG-proj + attention + out-proj + residual -----
// block = (i = bx>>1, jh = bx&1); 4 waves; wave handles 32 j's and 64 k-pos.
#define KS 40     // Kh row stride (ushorts): 80B, 16B-aligned
#define VS 272    // VTh row stride: 544B, 16B-aligned
#define PS 40     // Pst row stride
__global__ __launch_bounds__(256, 2) void k_fused(
    const ushort* __restrict__ x, const ushort* __restrict__ WT,
    const ushort* __restrict__ WoT, const ushort* __restrict__ biasT,
    const float* __restrict__ bg, const float* __restrict__ bo,
    const float* __restrict__ in0, float* __restrict__ out) {
  __shared__ __align__(16) ushort Kh[256 * KS];     // K for current head: [kpos][d0..32]
  __shared__ __align__(16) ushort VTh[32 * VS];     // V^T for current head: [d][kpos]
  __shared__ __align__(16) ushort Pst[4][16 * PS];  // per-wave staging (Q / P / ctx)
  int i  = blockIdx.x >> 1;
  int jh = blockIdx.x & 1;
  int t = threadIdx.x, wv = t >> 6, lane = t & 63;
  int n = lane & 15, g = lane >> 4;
  int jw = jh * 128 + wv * 32;    // wave's first query j
  int kw = wv * 64;               // wave's K/V kpos range
  const ushort* xr = x + (size_t)i * 256 * 128;
  ushort* Pw = Pst[wv];

  // ---- Phase 0: Q A-frags + gate (both register-resident) ----
  bf16x8 qa[2][4];        // [jt][h]
  uint2  gate[2][8];      // [jt][ct] C-layout packed bf16 (r0..r3)
  #pragma unroll
  for (int rt = 0; rt < 2; rt++) {
    bf16x8 a4[4];
    #pragma unroll
    for (int kc = 0; kc < 4; kc++)
      a4[kc] = *(const bf16x8*)(xr + (size_t)(jw + rt * 16 + n) * 128 + kc * 32 + g * 8);
    // gate = sigmoid(x@Wg + bg), kept in C-layout regs
    #pragma unroll
    for (int ct = 0; ct < 8; ct++) {
      f32x4 c = {0.f, 0.f, 0.f, 0.f};
      #pragma unroll
      for (int kc = 0; kc < 4; kc++) {
        bf16x8 b = *(const bf16x8*)(WT + (size_t)(384 + ct * 16 + n) * 128 + kc * 32 + g * 8);
        c = __builtin_amdgcn_mfma_f32_16x16x32_bf16(a4[kc], b, c, 0, 0, 0);
      }
      float bgn = bg[ct * 16 + n];
      float s0 = 1.0f / (1.0f + __expf(-(c[0] + bgn)));
      float s1 = 1.0f / (1.0f + __expf(-(c[1] + bgn)));
      float s2 = 1.0f / (1.0f + __expf(-(c[2] + bgn)));
      float s3 = 1.0f / (1.0f + __expf(-(c[3] + bgn)));
      gate[rt][ct].x = pack2(s0, s1);
      gate[rt][ct].y = pack2(s2, s3);
    }
    // Q per head: C-layout -> A-frag via per-wave staging
    #pragma unroll
    for (int h = 0; h < 4; h++) {
      lgkm_wait();
      #pragma unroll
      for (int ct = 0; ct < 2; ct++) {
        f32x4 c = {0.f, 0.f, 0.f, 0.f};
        #pragma unroll
        for (int kc = 0; kc < 4; kc++) {
          bf16x8 b = *(const bf16x8*)(WT + (size_t)(h * 32 + ct * 16 + n) * 128 + kc * 32 + g * 8);
          c = __builtin_amdgcn_mfma_f32_16x16x32_bf16(a4[kc], b, c, 0, 0, 0);
        }
        #pragma unroll
        for (int r = 0; r < 4; r++)
          Pw[(g * 4 + r) * PS + ct * 16 + n] = f2bf(c[r]);
      }
      lgkm_wait();
      qa[rt][h] = *(const bf16x8*)(&Pw[n * PS + g * 8]);
    }
  }

  // ---- Main loop over heads ----
  uint2 ctxreg[2][8];   // [jt][h*2+nt] gated ctx, C-layout packed bf16
  for (int h = 0; h < 4; h++) {
    // build K (natural) and V^T (transposed, free via packed b64) for this head
    #pragma unroll
    for (int rt = 0; rt < 4; rt++) {
      int k0 = kw + rt * 16;
      bf16x8 a4[4];
      #pragma unroll
      for (int kc = 0; kc < 4; kc++)
        a4[kc] = *(const bf16x8*)(xr + (size_t)(k0 + n) * 128 + kc * 32 + g * 8);
      #pragma unroll
      for (int ct = 0; ct < 2; ct++) {
        f32x4 ck = {0.f, 0.f, 0.f, 0.f}, cv = {0.f, 0.f, 0.f, 0.f};
        #pragma unroll
        for (int kc = 0; kc < 4; kc++) {
          bf16x8 bk = *(const bf16x8*)(WT + (size_t)(128 + h * 32 + ct * 16 + n) * 128 + kc * 32 + g * 8);
          bf16x8 bv = *(const bf16x8*)(WT + (size_t)(256 + h * 32 + ct * 16 + n) * 128 + kc * 32 + g * 8);
          ck = __builtin_amdgcn_mfma_f32_16x16x32_bf16(a4[kc], bk, ck, 0, 0, 0);
          cv = __builtin_amdgcn_mfma_f32_16x16x32_bf16(a4[kc], bv, cv, 0, 0, 0);
        }
        #pragma unroll
        for (int r = 0; r < 4; r++)
          Kh[(k0 + g * 4 + r) * KS + ct * 16 + n] = f2bf(ck[r]);
        uint2 vp; vp.x = pack2(cv[0], cv[1]); vp.y = pack2(cv[2], cv[3]);
        *(uint2*)(&VTh[(ct * 16 + n) * VS + k0 + g * 4]) = vp;
      }
    }
    __syncthreads();
    #pragma unroll
    for (int jt = 0; jt < 2; jt++) {
      int j0 = jw + jt * 16;
      // QK^T + bias (bf16 vector loads from biasT[h][k][j])
      f32x4 s[16];
      #pragma unroll
      for (int kt = 0; kt < 16; kt++) {
        uint2 bv = *(const uint2*)(biasT + (size_t)h * NPOS + (size_t)(kt * 16 + n) * 256 + j0 + g * 4);
        bf16x8 bk = *(const bf16x8*)(&Kh[(kt * 16 + n) * KS + g * 8]);
        f32x4 c = {0.f, 0.f, 0.f, 0.f};
        c = __builtin_amdgcn_mfma_f32_16x16x32_bf16(qa[jt][h], bk, c, 0, 0, 0);
        c[0] += bf2f((unsigned short)(bv.x & 0xffff));
        c[1] += bf2f((unsigned short)(bv.x >> 16));
        c[2] += bf2f((unsigned short)(bv.y & 0xffff));
        c[3] += bf2f((unsigned short)(bv.y >> 16));
        s[kt] = c;
      }
      // softmax over 256 keys (in-lane over kt, cross-lane over n within g-group)
      float inv[4];
      #pragma unroll
      for (int r = 0; r < 4; r++) {
        float m = s[0][r];
        #pragma unroll
        for (int kt = 1; kt < 16; kt++) m = fmaxf(m, s[kt][r]);
        #pragma unroll
        for (int xm = 1; xm < 16; xm <<= 1) m = fmaxf(m, __shfl_xor(m, xm, 16));
        float sm = 0.f;
        #pragma unroll
        for (int kt = 0; kt < 16; kt++) {
          float p = __expf(s[kt][r] - m);
          s[kt][r] = p;
          sm += p;
        }
        #pragma unroll
        for (int xm = 1; xm < 16; xm <<= 1) sm += __shfl_xor(sm, xm, 16);
        inv[r] = 1.0f / sm;
      }
      // PV, chunked through per-wave staging (C-layout -> A-frag)
      f32x4 ctx0 = {0.f, 0.f, 0.f, 0.f}, ctx1 = {0.f, 0.f, 0.f, 0.f};
      #pragma unroll
      for (int kc8 = 0; kc8 < 8; kc8++) {
        lgkm_wait();
        #pragma unroll
        for (int half = 0; half < 2; half++) {
          int kt = kc8 * 2 + half;
          #pragma unroll
          for (int r = 0; r < 4; r++)
            Pw[(g * 4 + r) * PS + half * 16 + n] = f2bf(s[kt][r] * inv[r]);
        }
        lgkm_wait();
        bf16x8 ap  = *(const bf16x8*)(&Pw[n * PS + g * 8]);
        bf16x8 vb0 = *(const bf16x8*)(&VTh[(n)      * VS + kc8 * 32 + g * 8]);
        bf16x8 vb1 = *(const bf16x8*)(&VTh[(16 + n) * VS + kc8 * 32 + g * 8]);
        ctx0 = __builtin_amdgcn_mfma_f32_16x16x32_bf16(ap, vb0, ctx0, 0, 0, 0);
        ctx1 = __builtin_amdgcn_mfma_f32_16x16x32_bf16(ap, vb1, ctx1, 0, 0, 0);
      }
      // gate (registers, same C-layout) and stash packed ctx
      uint2 g0 = gate[jt][h * 2 + 0], g1 = gate[jt][h * 2 + 1];
      uint2 c0, c1;
      c0.x = pack2(ctx0[0] * bf2f((unsigned short)(g0.x & 0xffff)),
                   ctx0[1] * bf2f((unsigned short)(g0.x >> 16)));
      c0.y = pack2(ctx0[2] * bf2f((unsigned short)(g0.y & 0xffff)),
                   ctx0[3] * bf2f((unsigned short)(g0.y >> 16)));
      c1.x = pack2(ctx1[0] * bf2f((unsigned short)(g1.x & 0xffff)),
                   ctx1[1] * bf2f((unsigned short)(g1.x >> 16)));
      c1.y = pack2(ctx1[2] * bf2f((unsigned short)(g1.y & 0xffff)),
                   ctx1[3] * bf2f((unsigned short)(g1.y >> 16)));
      ctxreg[jt][h * 2 + 0] = c0;
      ctxreg[jt][h * 2 + 1] = c1;
    }
    if (h < 3) __syncthreads();
  }

  // ---- Phase 3: output projection + bias + residual (registers -> staging) --
  #pragma unroll
  for (int jt = 0; jt < 2; jt++) {
    f32x4 acc[8];
    #pragma unroll
    for (int nt = 0; nt < 8; nt++) acc[nt] = (f32x4){0.f, 0.f, 0.f, 0.f};
    #pragma unroll
    for (int kc = 0; kc < 4; kc++) {
      lgkm_wait();
      #pragma unroll
      for (int half = 0; half < 2; half++) {
        uint2 cv = ctxreg[jt][kc * 2 + half];
        Pw[(g * 4 + 0) * PS + half * 16 + n] = (ushort)(cv.x & 0xffff);
        Pw[(g * 4 + 1) * PS + half * 16 + n] = (ushort)(cv.x >> 16);
        Pw[(g * 4 + 2) * PS + half * 16 + n] = (ushort)(cv.y & 0xffff);
        Pw[(g * 4 + 3) * PS + half * 16 + n] = (ushort)(cv.y >> 16);
      }
      lgkm_wait();
      bf16x8 ca = *(const bf16x8*)(&Pw[n * PS + g * 8]);
      #pragma unroll
      for (int nt = 0; nt < 8; nt++) {
        bf16x8 b = *(const bf16x8*)(WoT + (size_t)(nt * 16 + n) * 128 + kc * 32 + g * 8);
        acc[nt] = __builtin_amdgcn_mfma_f32_16x16x32_bf16(ca, b, acc[nt], 0, 0, 0);
      }
    }
    #pragma unroll
    for (int nt = 0; nt < 8; nt++) {
      float bov = bo[nt * 16 + n];
      #pragma unroll
      for (int r = 0; r < 4; r++) {
        int j = jw + jt * 16 + g * 4 + r;
        size_t o = ((size_t)i * 256 + j) * 128 + nt * 16 + n;
        out[o] = acc[nt][r] + bov + in0[o];
      }
    }
  }
}

extern "C" void kernel_launch(void* const* d_in, const int* in_sizes, int n_in,
                              void* d_out, int out_size, void* d_ws, size_t ws_size,
                              hipStream_t stream) {
  const float* in0   = (const float*)d_in[0];
  const float* gamma = (const float*)d_in[1];
  const float* beta  = (const float*)d_in[2];
  const float* Wq    = (const float*)d_in[3];
  const float* Wk    = (const float*)d_in[4];
  const float* Wv    = (const float*)d_in[5];
  const float* Wb    = (const float*)d_in[6];
  const float* Wg    = (const float*)d_in[7];
  const float* bg    = (const float*)d_in[8];
  const float* Wo    = (const float*)d_in[9];
  const float* bo    = (const float*)d_in[10];
  float* out = (float*)d_out;
  char* ws = (char*)d_ws;

  const size_t MB = 1024 * 1024;
  ushort* xbuf  = (ushort*)(ws);                       // 16 MB: LN(x) bf16 [pos][128]
  ushort* biasT = (ushort*)(ws + 16 * MB);             // 512 KB: [h][k*256+j] bf16
  ushort* WT    = (ushort*)(ws + 17 * MB);             // 128 KB
  ushort* WoT   = (ushort*)(ws + 17 * MB + 128 * 1024);// 32 KB

  k_pack <<<320, 256, 0, stream>>>(Wq, Wk, Wv, Wg, Wo, WT, WoT);
  k_ln   <<<1024, 256, 0, stream>>>(in0, gamma, beta, Wb, xbuf, biasT);
  k_fused<<<512, 256, 0, stream>>>(xbuf, WT, WoT, biasT, bg, bo, in0, out);
}

// Round 5
// 276.303 us; speedup vs baseline: 1.1660x; 1.1660x over previous
//
#include <hip/hip_runtime.h>

#define LDIM 256
#define NPOS 65536   // 256*256

typedef __attribute__((ext_vector_type(8))) short bf16x8;
typedef __attribute__((ext_vector_type(4))) float f32x4;

static __device__ __forceinline__ unsigned short f2bf(float f) {
  union { float f; unsigned int u; } v; v.f = f;
  unsigned int r = v.u + 0x7fffu + ((v.u >> 16) & 1u);
  return (unsigned short)(r >> 16);
}
static __device__ __forceinline__ float bf2f(unsigned short u) {
  union { unsigned int u; float f; } v; v.u = ((unsigned int)u) << 16;
  return v.f;
}
static __device__ __forceinline__ unsigned int pack2(float a, float b) {
  return (unsigned int)f2bf(a) | ((unsigned int)f2bf(b) << 16);
}
static __device__ __forceinline__ void lgkm_wait() {
  __asm__ volatile("s_waitcnt lgkmcnt(0)" ::: "memory");
}

// ---------------- K0: pack transposed bf16 weights ----------------
__global__ void k_pack(const float* __restrict__ Wq, const float* __restrict__ Wk,
                       const float* __restrict__ Wv, const float* __restrict__ Wg,
                       const float* __restrict__ Wo,
                       ushort* __restrict__ WT, ushort* __restrict__ WoT) {
  int idx = blockIdx.x * blockDim.x + threadIdx.x;
  if (idx < 512 * 128) {
    int n = idx >> 7, k = idx & 127;
    int nn = n & 127;
    float val;
    if (n < 128)      val = Wq[k * 128 + nn] * 0.17677669529663687f; // fold 1/sqrt(D)
    else if (n < 256) val = Wk[k * 128 + nn];
    else if (n < 384) val = Wv[k * 128 + nn];
    else              val = Wg[k * 128 + nn];
    WT[idx] = f2bf(val);
  } else if (idx < 512 * 128 + 128 * 128) {
    int j = idx - 512 * 128;
    int n = j >> 7, k = j & 127;
    WoT[j] = f2bf(Wo[k * 128 + n]);
  }
}

// ---------------- K1: fused LN + bias + QKVG proj, zero barriers ----------
// block = 64 positions (grid 1024); wave = 16 rows, all 512 cols.
// Lane (n,g): row m0+n, holds cols {kc*32 + g*8 + e} = exactly its A-frag data.
// Outputs: q,k [i][h][j][d]; vT [i][h][d][k]; gate [pos][128]; biasT[h][k*256+j] bf16
__global__ __launch_bounds__(256, 3) void k_lnproj(
    const float* __restrict__ in, const float* __restrict__ gamma,
    const float* __restrict__ beta, const float* __restrict__ Wb,
    const ushort* __restrict__ WT, const float* __restrict__ bg,
    ushort* __restrict__ q, ushort* __restrict__ kmat, ushort* __restrict__ vT,
    ushort* __restrict__ gate, ushort* __restrict__ biasT) {
  __shared__ __align__(16) ushort stg[4][3072];   // 6 KB per-wave staging
  int t = threadIdx.x, wv = t >> 6, lane = t & 63;
  int n = lane & 15, g = lane >> 4;
  int row0 = blockIdx.x * 64;
  int i = row0 >> 8, j0b = row0 & 255;
  int m0 = wv * 16;
  int myrow = row0 + m0 + n;
  const float* rp = in + (size_t)myrow * 128;

  // ---- LN in registers ----
  float xv[32];
  float s = 0.f, ss = 0.f;
  #pragma unroll
  for (int kc = 0; kc < 4; kc++)
    #pragma unroll
    for (int pr = 0; pr < 2; pr++) {
      float4 v = *(const float4*)(rp + kc * 32 + g * 8 + pr * 4);
      int o = kc * 8 + pr * 4;
      xv[o] = v.x; xv[o+1] = v.y; xv[o+2] = v.z; xv[o+3] = v.w;
      s  += v.x + v.y + v.z + v.w;
      ss += v.x*v.x + v.y*v.y + v.z*v.z + v.w*v.w;
    }
  s  += __shfl_xor(s, 16, 64);  s  += __shfl_xor(s, 32, 64);
  ss += __shfl_xor(ss, 16, 64); ss += __shfl_xor(ss, 32, 64);
  float mu  = s * (1.0f / 128.0f);
  float var = ss * (1.0f / 128.0f) - mu * mu;
  float rs  = rsqrtf(var + 1e-5f);
  // normalize + pairwise-bias einsum
  float p0 = 0.f, p1 = 0.f, p2 = 0.f, p3 = 0.f;
  #pragma unroll
  for (int kc = 0; kc < 4; kc++)
    #pragma unroll
    for (int pr = 0; pr < 2; pr++) {
      int c0 = kc * 32 + g * 8 + pr * 4;
      float4 g4 = *(const float4*)(gamma + c0);
      float4 b4 = *(const float4*)(beta + c0);
      int o = kc * 8 + pr * 4;
      #pragma unroll
      for (int r = 0; r < 4; r++) {
        float xn = (xv[o + r] - mu) * rs * (&g4.x)[r] + (&b4.x)[r];
        xv[o + r] = xn;
        float4 w = ((const float4*)Wb)[c0 + r];
        p0 += xn * w.x; p1 += xn * w.y; p2 += xn * w.z; p3 += xn * w.w;
      }
    }
  p0 += __shfl_xor(p0, 16, 64); p0 += __shfl_xor(p0, 32, 64);
  p1 += __shfl_xor(p1, 16, 64); p1 += __shfl_xor(p1, 32, 64);
  p2 += __shfl_xor(p2, 16, 64); p2 += __shfl_xor(p2, 32, 64);
  p3 += __shfl_xor(p3, 16, 64); p3 += __shfl_xor(p3, 32, 64);
  if (g == 0) {
    // pos=(jq=myrow>>8, kk=myrow&255); biasT[h][kk*256+jq]
    size_t o = (size_t)(myrow & 255) * 256 + (myrow >> 8);
    biasT[0 * NPOS + o] = f2bf(p0);
    biasT[1 * NPOS + o] = f2bf(p1);
    biasT[2 * NPOS + o] = f2bf(p2);
    biasT[3 * NPOS + o] = f2bf(p3);
  }
  // A-frags (lane already holds exactly its frag data)
  bf16x8 a[4];
  #pragma unroll
  for (int kc = 0; kc < 4; kc++)
    #pragma unroll
    for (int e = 0; e < 8; e++) a[kc][e] = (short)f2bf(xv[kc * 8 + e]);

  ushort* st = stg[wv];
  // ---- 4 sections: q | k | v | gate ----
  #pragma unroll
  for (int s4 = 0; s4 < 4; s4++) {
    f32x4 acc[8];
    #pragma unroll
    for (int ntl = 0; ntl < 8; ntl++) {
      f32x4 c = {0.f, 0.f, 0.f, 0.f};
      #pragma unroll
      for (int kc = 0; kc < 4; kc++) {
        bf16x8 b = *(const bf16x8*)(WT + (size_t)(s4 * 128 + ntl * 16 + n) * 128 + kc * 32 + g * 8);
        c = __builtin_amdgcn_mfma_f32_16x16x32_bf16(a[kc], b, c, 0, 0, 0);
      }
      acc[ntl] = c;
    }
    lgkm_wait();   // prior section's drain reads complete before overwrite
    if (s4 == 2) {
      // V: stage transposed [128 hd][24 k-slot]
      #pragma unroll
      for (int ntl = 0; ntl < 8; ntl++) {
        uint2 vp;
        vp.x = pack2(acc[ntl][0], acc[ntl][1]);
        vp.y = pack2(acc[ntl][2], acc[ntl][3]);
        *(uint2*)(&st[(ntl * 16 + n) * 24 + g * 4]) = vp;
      }
      lgkm_wait();
      #pragma unroll
      for (int it = 0; it < 4; it++) {
        int c = it * 64 + lane;
        int hd = c >> 1, half = c & 1;
        bf16x8 vv = *(const bf16x8*)(&st[hd * 24 + half * 8]);
        int h = hd >> 5, d = hd & 31;
        *(bf16x8*)(vT + ((size_t)(i * 4 + h) * 32 + d) * 256 + j0b + m0 + half * 8) = vv;
      }
    } else {
      #pragma unroll
      for (int ntl = 0; ntl < 8; ntl++) {
        #pragma unroll
        for (int r = 0; r < 4; r++) {
          float val = acc[ntl][r];
          if (s4 == 3) val = 1.0f / (1.0f + __expf(-(val + bg[ntl * 16 + n])));
          st[(g * 4 + r) * 136 + ntl * 16 + n] = f2bf(val);
        }
      }
      lgkm_wait();
      if (s4 == 3) {
        #pragma unroll
        for (int it = 0; it < 4; it++) {
          int c = it * 64 + lane;
          int row = c >> 4, off = (c & 15) * 8;
          *(bf16x8*)(gate + (size_t)(row0 + m0 + row) * 128 + off) =
              *(const bf16x8*)(&st[row * 136 + off]);
        }
      } else {
        ushort* dst = (s4 == 0) ? q : kmat;
        int row = lane >> 2, off = (lane & 3) * 8;
        #pragma unroll
        for (int h = 0; h < 4; h++)
          *(bf16x8*)(dst + ((size_t)(i * 4 + h) * 256 + j0b + m0 + row) * 32 + off) =
              *(const bf16x8*)(&st[row * 136 + h * 32 + off]);
      }
    }
  }
}

// ---------------- K2: attention per (i,h); compact operands; no barriers ----
#define SP 264
__global__ __launch_bounds__(256, 3) void k_attn(
    const ushort* __restrict__ q, const ushort* __restrict__ kmat,
    const ushort* __restrict__ vT, const ushort* __restrict__ gate,
    const ushort* __restrict__ biasT, ushort* __restrict__ gctx) {
  __shared__ __align__(16) ushort Psh[4][16 * SP];   // per-wave P / ctx stage
  int i = blockIdx.x >> 2, h = blockIdx.x & 3;
  int t = threadIdx.x, wv = t >> 6, lane = t & 63;
  int n = lane & 15, g = lane >> 4;
  const ushort* qb = q    + (size_t)(i * 4 + h) * 256 * 32;
  const ushort* kb = kmat + (size_t)(i * 4 + h) * 256 * 32;
  const ushort* vb = vT   + (size_t)(i * 4 + h) * 32 * 256;
  const ushort* bb = biasT + (size_t)h * NPOS;
  ushort* Pw = Psh[wv];

  for (int jj = 0; jj < 4; jj++) {
    int j0 = wv * 64 + jj * 16;
    bf16x8 aq = *(const bf16x8*)(qb + (size_t)(j0 + n) * 32 + g * 8);
    f32x4 s[16];
    #pragma unroll
    for (int kt = 0; kt < 16; kt++) {
      uint2 bv = *(const uint2*)(bb + (size_t)(kt * 16 + n) * 256 + j0 + g * 4);
      bf16x8 bk = *(const bf16x8*)(kb + (size_t)(kt * 16 + n) * 32 + g * 8);
      f32x4 c = {0.f, 0.f, 0.f, 0.f};
      c = __builtin_amdgcn_mfma_f32_16x16x32_bf16(aq, bk, c, 0, 0, 0);
      c[0] += bf2f((unsigned short)(bv.x & 0xffff));
      c[1] += bf2f((unsigned short)(bv.x >> 16));
      c[2] += bf2f((unsigned short)(bv.y & 0xffff));
      c[3] += bf2f((unsigned short)(bv.y >> 16));
      s[kt] = c;
    }
    float inv[4];
    #pragma unroll
    for (int r = 0; r < 4; r++) {
      float m = s[0][r];
      #pragma unroll
      for (int kt = 1; kt < 16; kt++) m = fmaxf(m, s[kt][r]);
      #pragma unroll
      for (int xm = 1; xm < 16; xm <<= 1) m = fmaxf(m, __shfl_xor(m, xm, 16));
      float sm = 0.f;
      #pragma unroll
      for (int kt = 0; kt < 16; kt++) {
        float p = __expf(s[kt][r] - m);
        s[kt][r] = p;
        sm += p;
      }
      #pragma unroll
      for (int xm = 1; xm < 16; xm <<= 1) sm += __shfl_xor(sm, xm, 16);
      inv[r] = 1.0f / sm;
    }
    lgkm_wait();   // previous iteration's Pw/CT reads done
    #pragma unroll
    for (int kt = 0; kt < 16; kt++)
      #pragma unroll
      for (int r = 0; r < 4; r++)
        Pw[(g * 4 + r) * SP + kt * 16 + n] = f2bf(s[kt][r] * inv[r]);
    lgkm_wait();
    f32x4 ctx0 = {0.f, 0.f, 0.f, 0.f}, ctx1 = {0.f, 0.f, 0.f, 0.f};
    #pragma unroll
    for (int kc8 = 0; kc8 < 8; kc8++) {
      bf16x8 ap = *(const bf16x8*)(&Pw[n * SP + kc8 * 32 + g * 8]);
      bf16x8 v0 = *(const bf16x8*)(vb + (size_t)(n)      * 256 + kc8 * 32 + g * 8);
      bf16x8 v1 = *(const bf16x8*)(vb + (size_t)(16 + n) * 256 + kc8 * 32 + g * 8);
      ctx0 = __builtin_amdgcn_mfma_f32_16x16x32_bf16(ap, v0, ctx0, 0, 0, 0);
      ctx1 = __builtin_amdgcn_mfma_f32_16x16x32_bf16(ap, v1, ctx1, 0, 0, 0);
    }
    float* CT = (float*)Pw;
    lgkm_wait();
    #pragma unroll
    for (int r = 0; r < 4; r++) {
      CT[(g * 4 + r) * 36 +      n] = ctx0[r];
      CT[(g * 4 + r) * 36 + 16 + n] = ctx1[r];
    }
    lgkm_wait();
    {
      int row = lane >> 2, part = lane & 3;
      int j = j0 + row;
      size_t o = ((size_t)i * 256 + j) * 128 + h * 32 + part * 8;
      bf16x8 gt = *(const bf16x8*)(gate + o);
      bf16x8 outp;
      #pragma unroll
      for (int e = 0; e < 8; e++)
        outp[e] = (short)f2bf(CT[row * 36 + part * 8 + e] * bf2f((unsigned short)gt[e]));
      *(bf16x8*)(gctx + o) = outp;
    }
  }
}

// ---------------- K3: out-proj + bias + residual; coalesced; no barriers ----
__global__ __launch_bounds__(256, 4) void k_out(
    const ushort* __restrict__ gctx, const ushort* __restrict__ WoT,
    const float* __restrict__ bo, const float* __restrict__ in0,
    float* __restrict__ out) {
  __shared__ __align__(16) float CTs[4][16 * 132];   // per-wave f32 stage (8.25KB)
  int t = threadIdx.x, wv = t >> 6, lane = t & 63;
  int n = lane & 15, g = lane >> 4;
  int row0 = blockIdx.x * 64;
  int m0 = wv * 16;
  bf16x8 a[4];
  #pragma unroll
  for (int kc = 0; kc < 4; kc++)
    a[kc] = *(const bf16x8*)(gctx + (size_t)(row0 + m0 + n) * 128 + kc * 32 + g * 8);
  float* CT = CTs[wv];
  #pragma unroll
  for (int ntl = 0; ntl < 8; ntl++) {
    f32x4 acc = {0.f, 0.f, 0.f, 0.f};
    #pragma unroll
    for (int kc = 0; kc < 4; kc++) {
      bf16x8 b = *(const bf16x8*)(WoT + (size_t)(ntl * 16 + n) * 128 + kc * 32 + g * 8);
      acc = __builtin_amdgcn_mfma_f32_16x16x32_bf16(a[kc], b, acc, 0, 0, 0);
    }
    float bov = bo[ntl * 16 + n];
    #pragma unroll
    for (int r = 0; r < 4; r++)
      CT[(g * 4 + r) * 132 + ntl * 16 + n] = acc[r] + bov;
  }
  lgkm_wait();
  #pragma unroll
  for (int it = 0; it < 8; it++) {
    int c = it * 64 + lane;
    int row = c >> 5, off = (c & 31) * 4;
    f32x4 v = *(const f32x4*)(&CT[row * 132 + off]);
    size_t o = (size_t)(row0 + m0 + row) * 128 + off;
    f32x4 r4 = *(const f32x4*)(in0 + o);
    v[0] += r4[0]; v[1] += r4[1]; v[2] += r4[2]; v[3] += r4[3];
    *(f32x4*)(out + o) = v;
  }
}

extern "C" void kernel_launch(void* const* d_in, const int* in_sizes, int n_in,
                              void* d_out, int out_size, void* d_ws, size_t ws_size,
                              hipStream_t stream) {
  const float* in0   = (const float*)d_in[0];
  const float* gamma = (const float*)d_in[1];
  const float* beta  = (const float*)d_in[2];
  const float* Wq    = (const float*)d_in[3];
  const float* Wk    = (const float*)d_in[4];
  const float* Wv    = (const float*)d_in[5];
  const float* Wb    = (const float*)d_in[6];
  const float* Wg    = (const float*)d_in[7];
  const float* bg    = (const float*)d_in[8];
  const float* Wo    = (const float*)d_in[9];
  const float* bo    = (const float*)d_in[10];
  float* out = (float*)d_out;
  char* ws = (char*)d_ws;

  const size_t MB = 1024 * 1024;
  ushort* qbuf  = (ushort*)(ws);              // 16 MB: [i][h][j][d]
  ushort* kbuf  = (ushort*)(ws + 16 * MB);    // 16 MB: [i][h][k][d]
  ushort* vTbuf = (ushort*)(ws + 32 * MB);    // 16 MB: [i][h][d][k]
  ushort* gbuf  = (ushort*)(ws + 48 * MB);    // 16 MB: gate [pos][128]
  ushort* gctx  = (ushort*)(ws + 64 * MB);    // 16 MB: [pos][128]
  ushort* biasT = (ushort*)(ws + 80 * MB);    // 512 KB: [h][k*256+j]
  ushort* WT    = (ushort*)(ws + 81 * MB);    // 128 KB
  ushort* WoT   = (ushort*)(ws + 81 * MB + 128 * 1024);  // 32 KB

  k_pack  <<<320, 256, 0, stream>>>(Wq, Wk, Wv, Wg, Wo, WT, WoT);
  k_lnproj<<<1024, 256, 0, stream>>>(in0, gamma, beta, Wb, WT, bg,
                                     qbuf, kbuf, vTbuf, gbuf, biasT);
  k_attn  <<<1024, 256, 0, stream>>>(qbuf, kbuf, vTbuf, gbuf, biasT, gctx);
  k_out   <<<1024, 256, 0, stream>>>(gctx, WoT, bo, in0, out);
}

// Round 6
// 270.169 us; speedup vs baseline: 1.1924x; 1.0227x over previous
//
#include <hip/hip_runtime.h>

#define NPOS 65536   // 256*256

typedef __attribute__((ext_vector_type(8))) short bf16x8;
typedef __attribute__((ext_vector_type(4))) float f32x4;

#if __has_builtin(__builtin_amdgcn_exp2f)
#define EXP2F(x) __builtin_amdgcn_exp2f(x)
#else
#define EXP2F(x) __expf((x) * 0.6931471805599453f)
#endif
#if __has_builtin(__builtin_amdgcn_rcpf)
#define RCPF(x) __builtin_amdgcn_rcpf(x)
#else
#define RCPF(x) (1.0f / (x))
#endif

static __device__ __forceinline__ unsigned short f2bf(float f) {
  union { float f; unsigned int u; } v; v.f = f;
  unsigned int r = v.u + 0x7fffu + ((v.u >> 16) & 1u);
  return (unsigned short)(r >> 16);
}
static __device__ __forceinline__ float bf2f(unsigned short u) {
  union { unsigned int u; float f; } v; v.u = ((unsigned int)u) << 16;
  return v.f;
}
static __device__ __forceinline__ float lo_bf(unsigned int u) {
  union { unsigned int u; float f; } v; v.u = u << 16; return v.f;
}
static __device__ __forceinline__ float hi_bf(unsigned int u) {
  union { unsigned int u; float f; } v; v.u = u & 0xffff0000u; return v.f;
}
static __device__ __forceinline__ unsigned int pack2(float a, float b) {
  return (unsigned int)f2bf(a) | ((unsigned int)f2bf(b) << 16);
}
// (hi.bf16_trunc << 16) | lo.bf16_trunc  — 1 instruction (v_perm_b32)
static __device__ __forceinline__ unsigned int permpack(float hi, float lo) {
  union { float f; unsigned int u; } a, b;
  a.f = hi; b.f = lo;
#if __has_builtin(__builtin_amdgcn_perm)
  return __builtin_amdgcn_perm(a.u, b.u, 0x07060302u);
#else
  return (a.u & 0xffff0000u) | (b.u >> 16);
#endif
}

// ---------------- K0: pack transposed bf16 weights ----------------
// Wq gets 1/sqrt(32) * log2(e) folded (softmax uses exp2, no max-sub).
__global__ void k_pack(const float* __restrict__ Wq, const float* __restrict__ Wk,
                       const float* __restrict__ Wv, const float* __restrict__ Wg,
                       const float* __restrict__ Wo,
                       ushort* __restrict__ WT, ushort* __restrict__ WoT) {
  int idx = blockIdx.x * blockDim.x + threadIdx.x;
  if (idx < 512 * 128) {
    int n = idx >> 7, k = idx & 127;
    int nn = n & 127;
    float val;
    if (n < 128)      val = Wq[k * 128 + nn] * (0.17677669529663687f * 1.4426950408889634f);
    else if (n < 256) val = Wk[k * 128 + nn];
    else if (n < 384) val = Wv[k * 128 + nn];
    else              val = Wg[k * 128 + nn];
    WT[idx] = f2bf(val);
  } else if (idx < 512 * 128 + 128 * 128) {
    int j = idx - 512 * 128;
    int n = j >> 7, k = j & 127;
    WoT[j] = f2bf(Wo[k * 128 + n]);
  }
}

// ---------------- K1: fused LN + bias + QKVG proj; 128 thr, no barriers -----
// block = 32 rows (grid 2048); wave = 16 rows. bias stored natural [h][pos]*log2e.
__global__ __launch_bounds__(128, 4) void k_lnproj(
    const float* __restrict__ in, const float* __restrict__ gamma,
    const float* __restrict__ beta, const float* __restrict__ Wb,
    const ushort* __restrict__ WT, const float* __restrict__ bg,
    ushort* __restrict__ q, ushort* __restrict__ kmat, ushort* __restrict__ vT,
    ushort* __restrict__ gate, ushort* __restrict__ biasB) {
  __shared__ __align__(16) ushort stg[2][3072];   // 6 KB per-wave staging
  int t = threadIdx.x, wv = t >> 6, lane = t & 63;
  int n = lane & 15, g = lane >> 4;
  int row0 = blockIdx.x * 32;
  int i = row0 >> 8, j0b = row0 & 255;
  int m0 = wv * 16;
  int myrow = row0 + m0 + n;
  const float* rp = in + (size_t)myrow * 128;

  // ---- LN in registers ----
  float xv[32];
  float s = 0.f, ss = 0.f;
  #pragma unroll
  for (int kc = 0; kc < 4; kc++)
    #pragma unroll
    for (int pr = 0; pr < 2; pr++) {
      float4 v = *(const float4*)(rp + kc * 32 + g * 8 + pr * 4);
      int o = kc * 8 + pr * 4;
      xv[o] = v.x; xv[o+1] = v.y; xv[o+2] = v.z; xv[o+3] = v.w;
      s  += v.x + v.y + v.z + v.w;
      ss += v.x*v.x + v.y*v.y + v.z*v.z + v.w*v.w;
    }
  s  += __shfl_xor(s, 16, 64);  s  += __shfl_xor(s, 32, 64);
  ss += __shfl_xor(ss, 16, 64); ss += __shfl_xor(ss, 32, 64);
  float mu  = s * (1.0f / 128.0f);
  float var = ss * (1.0f / 128.0f) - mu * mu;
  float rs  = rsqrtf(var + 1e-5f);
  float p0 = 0.f, p1 = 0.f, p2 = 0.f, p3 = 0.f;
  #pragma unroll
  for (int kc = 0; kc < 4; kc++)
    #pragma unroll
    for (int pr = 0; pr < 2; pr++) {
      int c0 = kc * 32 + g * 8 + pr * 4;
      float4 g4 = *(const float4*)(gamma + c0);
      float4 b4 = *(const float4*)(beta + c0);
      int o = kc * 8 + pr * 4;
      #pragma unroll
      for (int r = 0; r < 4; r++) {
        float xn = (xv[o + r] - mu) * rs * (&g4.x)[r] + (&b4.x)[r];
        xv[o + r] = xn;
        float4 w = ((const float4*)Wb)[c0 + r];
        p0 += xn * w.x; p1 += xn * w.y; p2 += xn * w.z; p3 += xn * w.w;
      }
    }
  p0 += __shfl_xor(p0, 16, 64); p0 += __shfl_xor(p0, 32, 64);
  p1 += __shfl_xor(p1, 16, 64); p1 += __shfl_xor(p1, 32, 64);
  p2 += __shfl_xor(p2, 16, 64); p2 += __shfl_xor(p2, 32, 64);
  p3 += __shfl_xor(p3, 16, 64); p3 += __shfl_xor(p3, 32, 64);
  if (g == 0) {
    const float l2e = 1.4426950408889634f;
    biasB[0 * NPOS + myrow] = f2bf(p0 * l2e);
    biasB[1 * NPOS + myrow] = f2bf(p1 * l2e);
    biasB[2 * NPOS + myrow] = f2bf(p2 * l2e);
    biasB[3 * NPOS + myrow] = f2bf(p3 * l2e);
  }
  bf16x8 a[4];
  #pragma unroll
  for (int kc = 0; kc < 4; kc++)
    #pragma unroll
    for (int e = 0; e < 8; e++) a[kc][e] = (short)f2bf(xv[kc * 8 + e]);

  ushort* st = stg[wv];
  // ---- 4 sections: q | k | v | gate ----
  #pragma unroll
  for (int s4 = 0; s4 < 4; s4++) {
    f32x4 acc[8];
    #pragma unroll
    for (int ntl = 0; ntl < 8; ntl++) {
      f32x4 c = {0.f, 0.f, 0.f, 0.f};
      #pragma unroll
      for (int kc = 0; kc < 4; kc++) {
        bf16x8 b = *(const bf16x8*)(WT + (size_t)(s4 * 128 + ntl * 16 + n) * 128 + kc * 32 + g * 8);
        c = __builtin_amdgcn_mfma_f32_16x16x32_bf16(a[kc], b, c, 0, 0, 0);
      }
      acc[ntl] = c;
    }
    if (s4 == 2) {
      // V: stage transposed [128 hd][24 k-slot]
      #pragma unroll
      for (int ntl = 0; ntl < 8; ntl++) {
        uint2 vp;
        vp.x = pack2(acc[ntl][1], acc[ntl][0]) ;
        vp.x = (unsigned int)f2bf(acc[ntl][0]) | ((unsigned int)f2bf(acc[ntl][1]) << 16);
        vp.y = (unsigned int)f2bf(acc[ntl][2]) | ((unsigned int)f2bf(acc[ntl][3]) << 16);
        *(uint2*)(&st[(ntl * 16 + n) * 24 + g * 4]) = vp;
      }
      #pragma unroll
      for (int it = 0; it < 4; it++) {
        int c = it * 64 + lane;
        int hd = c >> 1, half = c & 1;
        bf16x8 vv = *(const bf16x8*)(&st[hd * 24 + half * 8]);
        int h = hd >> 5, d = hd & 31;
        *(bf16x8*)(vT + ((size_t)(i * 4 + h) * 32 + d) * 256 + j0b + m0 + half * 8) = vv;
      }
    } else {
      #pragma unroll
      for (int ntl = 0; ntl < 8; ntl++) {
        #pragma unroll
        for (int r = 0; r < 4; r++) {
          float val = acc[ntl][r];
          if (s4 == 3) val = 1.0f / (1.0f + __expf(-(val + bg[ntl * 16 + n])));
          st[(g * 4 + r) * 136 + ntl * 16 + n] = f2bf(val);
        }
      }
      if (s4 == 3) {
        #pragma unroll
        for (int it = 0; it < 4; it++) {
          int c = it * 64 + lane;
          int row = c >> 4, off = (c & 15) * 8;
          *(bf16x8*)(gate + (size_t)(row0 + m0 + row) * 128 + off) =
              *(const bf16x8*)(&st[row * 136 + off]);
        }
      } else {
        ushort* dst = (s4 == 0) ? q : kmat;
        int row = lane >> 2, off = (lane & 3) * 8;
        #pragma unroll
        for (int h = 0; h < 4; h++)
          *(bf16x8*)(dst + ((size_t)(i * 4 + h) * 256 + j0b + m0 + row) * 32 + off) =
              *(const bf16x8*)(&st[row * 136 + h * 32 + off]);
      }
    }
  }
}

// ---------------- K2: attention, S^T orientation; no barriers, no max-sub ---
#define PST 40   // P-stage row stride (ushorts; 80B, 16B-aligned)
__global__ __launch_bounds__(256, 4) void k_attn(
    const ushort* __restrict__ q, const ushort* __restrict__ kmat,
    const ushort* __restrict__ vT, const ushort* __restrict__ gate,
    const ushort* __restrict__ biasB, ushort* __restrict__ gctx) {
  __shared__ __align__(16) float stg[4][16 * 36];   // 2.3KB/wave (P + ctx stage)
  int i = blockIdx.x >> 3, h = (blockIdx.x >> 1) & 3, jh = blockIdx.x & 1;
  int t = threadIdx.x, wv = t >> 6, lane = t & 63;
  int n = lane & 15, g = lane >> 4;
  const ushort* qb = q    + (size_t)(i * 4 + h) * 8192;
  const ushort* kb = kmat + (size_t)(i * 4 + h) * 8192;
  const ushort* vb = vT   + (size_t)(i * 4 + h) * 8192;
  const ushort* bb = biasB + (size_t)h * NPOS;
  ushort* Pw = (ushort*)stg[wv];
  float* CT = stg[wv];

  for (int jj = 0; jj < 2; jj++) {
    int j0 = jh * 128 + wv * 32 + jj * 16;
    // Q as B-operand (col = query), K as A-operand (row = key) -> S^T tiles
    bf16x8 bq = *(const bf16x8*)(qb + (size_t)(j0 + n) * 32 + g * 8);
    f32x4 s[16];
    #pragma unroll
    for (int kt = 0; kt < 16; kt++) {
      uint2 bv = *(const uint2*)(bb + (size_t)(j0 + n) * 256 + kt * 16 + g * 4);
      bf16x8 ak = *(const bf16x8*)(kb + (size_t)(kt * 16 + n) * 32 + g * 8);
      f32x4 c;
      c[0] = lo_bf(bv.x); c[1] = hi_bf(bv.x);
      c[2] = lo_bf(bv.y); c[3] = hi_bf(bv.y);
      s[kt] = __builtin_amdgcn_mfma_f32_16x16x32_bf16(ak, bq, c, 0, 0, 0);
    }
    // softmax: exp2 (log2e pre-folded), no max-sub (scores bounded ~|2|)
    f32x4 a4 = {0.f, 0.f, 0.f, 0.f};
    #pragma unroll
    for (int kt = 0; kt < 16; kt++) {
      #pragma unroll
      for (int r = 0; r < 4; r++) s[kt][r] = EXP2F(s[kt][r]);
      a4 += s[kt];
    }
    float sm = (a4[0] + a4[1]) + (a4[2] + a4[3]);
    sm += __shfl_xor(sm, 16, 64);
    sm += __shfl_xor(sm, 32, 64);
    float inv = RCPF(sm);   // per-lane: this lane's query = n
    // PV interleaved with P staging in 32-key chunks (wave-private LDS,
    // in-order DS pipe => no waits/barriers needed)
    f32x4 ctx0 = {0.f, 0.f, 0.f, 0.f}, ctx1 = {0.f, 0.f, 0.f, 0.f};
    #pragma unroll
    for (int c8 = 0; c8 < 8; c8++) {
      #pragma unroll
      for (int t2 = 0; t2 < 2; t2++) {
        int kt = c8 * 2 + t2;
        uint2 pp;
        pp.x = permpack(s[kt][1] * inv, s[kt][0] * inv);
        pp.y = permpack(s[kt][3] * inv, s[kt][2] * inv);
        *(uint2*)(&Pw[n * PST + t2 * 16 + g * 4]) = pp;   // row=query n, 4 keys
      }
      bf16x8 ap = *(const bf16x8*)(&Pw[n * PST + g * 8]);
      bf16x8 v0 = *(const bf16x8*)(vb + (size_t)n * 256 + c8 * 32 + g * 8);
      bf16x8 v1 = *(const bf16x8*)(vb + (size_t)(16 + n) * 256 + c8 * 32 + g * 8);
      ctx0 = __builtin_amdgcn_mfma_f32_16x16x32_bf16(ap, v0, ctx0, 0, 0, 0);
      ctx1 = __builtin_amdgcn_mfma_f32_16x16x32_bf16(ap, v1, ctx1, 0, 0, 0);
    }
    // ctx stage f32 (stride 36), gate applied on coalesced drain
    #pragma unroll
    for (int r = 0; r < 4; r++) {
      CT[(g * 4 + r) * 36 + n] = ctx0[r];
      CT[(g * 4 + r) * 36 + 16 + n] = ctx1[r];
    }
    {
      int row = lane >> 2, part = lane & 3;
      size_t o = ((size_t)i * 256 + j0 + row) * 128 + h * 32 + part * 8;
      bf16x8 gt = *(const bf16x8*)(gate + o);
      bf16x8 outp;
      #pragma unroll
      for (int e = 0; e < 8; e++)
        outp[e] = (short)f2bf(CT[row * 36 + part * 8 + e] * bf2f((unsigned short)gt[e]));
      *(bf16x8*)(gctx + o) = outp;
    }
  }
}

// ---------------- K3: out-proj + bias + residual; 128 thr, no barriers ------
__global__ __launch_bounds__(128, 4) void k_out(
    const ushort* __restrict__ gctx, const ushort* __restrict__ WoT,
    const float* __restrict__ bo, const float* __restrict__ in0,
    float* __restrict__ out) {
  __shared__ __align__(16) float CTs[2][16 * 132];
  int t = threadIdx.x, wv = t >> 6, lane = t & 63;
  int n = lane & 15, g = lane >> 4;
  int row0 = blockIdx.x * 32;
  int m0 = wv * 16;
  bf16x8 a[4];
  #pragma unroll
  for (int kc = 0; kc < 4; kc++)
    a[kc] = *(const bf16x8*)(gctx + (size_t)(row0 + m0 + n) * 128 + kc * 32 + g * 8);
  float* CT = CTs[wv];
  #pragma unroll
  for (int ntl = 0; ntl < 8; ntl++) {
    f32x4 acc = {0.f, 0.f, 0.f, 0.f};
    #pragma unroll
    for (int kc = 0; kc < 4; kc++) {
      bf16x8 b = *(const bf16x8*)(WoT + (size_t)(ntl * 16 + n) * 128 + kc * 32 + g * 8);
      acc = __builtin_amdgcn_mfma_f32_16x16x32_bf16(a[kc], b, acc, 0, 0, 0);
    }
    float bov = bo[ntl * 16 + n];
    #pragma unroll
    for (int r = 0; r < 4; r++)
      CT[(g * 4 + r) * 132 + ntl * 16 + n] = acc[r] + bov;
  }
  #pragma unroll
  for (int it = 0; it < 8; it++) {
    int c = it * 64 + lane;
    int row = c >> 5, off = (c & 31) * 4;
    f32x4 v = *(const f32x4*)(&CT[row * 132 + off]);
    size_t o = (size_t)(row0 + m0 + row) * 128 + off;
    f32x4 r4 = *(const f32x4*)(in0 + o);
    v[0] += r4[0]; v[1] += r4[1]; v[2] += r4[2]; v[3] += r4[3];
    *(f32x4*)(out + o) = v;
  }
}

extern "C" void kernel_launch(void* const* d_in, const int* in_sizes, int n_in,
                              void* d_out, int out_size, void* d_ws, size_t ws_size,
                              hipStream_t stream) {
  const float* in0   = (const float*)d_in[0];
  const float* gamma = (const float*)d_in[1];
  const float* beta  = (const float*)d_in[2];
  const float* Wq    = (const float*)d_in[3];
  const float* Wk    = (const float*)d_in[4];
  const float* Wv    = (const float*)d_in[5];
  const float* Wb    = (const float*)d_in[6];
  const float* Wg    = (const float*)d_in[7];
  const float* bg    = (const float*)d_in[8];
  const float* Wo    = (const float*)d_in[9];
  const float* bo    = (const float*)d_in[10];
  float* out = (float*)d_out;
  char* ws = (char*)d_ws;

  const size_t MB = 1024 * 1024;
  ushort* qbuf  = (ushort*)(ws);              // 16 MB: [ih][j][d]
  ushort* kbuf  = (ushort*)(ws + 16 * MB);    // 16 MB: [ih][k][d]
  ushort* vTbuf = (ushort*)(ws + 32 * MB);    // 16 MB: [ih][d][k]
  ushort* gbuf  = (ushort*)(ws + 48 * MB);    // 16 MB: gate [pos][128]
  ushort* gctx  = (ushort*)(ws + 64 * MB);    // 16 MB: [pos][128]
  ushort* biasB = (ushort*)(ws + 80 * MB);    // 512 KB: [h][j*256+k] * log2e
  ushort* WT    = (ushort*)(ws + 81 * MB);    // 128 KB
  ushort* WoT   = (ushort*)(ws + 81 * MB + 128 * 1024);  // 32 KB

  k_pack  <<<320, 256, 0, stream>>>(Wq, Wk, Wv, Wg, Wo, WT, WoT);
  k_lnproj<<<2048, 128, 0, stream>>>(in0, gamma, beta, Wb, WT, bg,
                                     qbuf, kbuf, vTbuf, gbuf, biasB);
  k_attn  <<<2048, 256, 0, stream>>>(qbuf, kbuf, vTbuf, gbuf, biasB, gctx);
  k_out   <<<2048, 128, 0, stream>>>(gctx, WoT, bo, in0, out);
}